// Round 8
// baseline (157.113 us; speedup 1.0000x reference)
//
#include <hip/hip_runtime.h>
#include <hip/hip_bf16.h>

// Round 8 = r7 + braided 2-tile software pipeline (triple-buffered LDS).
//  r7's wall (81us) = phase-locked tile body: LDS burst (QK) -> VALU burst
//  (softmax) -> LDS+MFMA (PV) -> barrier, all 16 waves/CU in lockstep; LDS
//  pipe ~55us busy is the floor. This round braids, per c-chunk:
//     softmax(kt) [VALU] | QK(kt+1) [LDS+MFMA] | PV(kt) [LDS+MFMA]
//  -- three independent streams in one wave, so pipes pack instead of burst.
//  Legal because fixed-base softmax has no cross-chunk dependency.
//  Ks/Vt triple-buffered (63.5KB LDS, still 2 blocks/CU, 16 waves/CU).
//  All per-chunk code (layouts, swizzles, staging) byte-identical to r7.

typedef __attribute__((ext_vector_type(8))) short bf16x8;
typedef __attribute__((ext_vector_type(4))) short bf16x4;
typedef __attribute__((ext_vector_type(4))) float f32x4;

#define B_ 2
#define S_ 2048
#define H_ 16
#define D_ 64
#define BQ 128
#define BK 64
#define NT (S_ / BK)
#define LDK 72                 // padded LDS row (144 B)
#define ROWSZ (H_ * D_)        // 1024 floats between s rows

#define LOG2E  1.44269504088896340736f
#define SCALE2 (0.125f * LOG2E)

__device__ __forceinline__ unsigned pack2(float a, float b) {
    union { __hip_bfloat162 h; unsigned u; } x;
    x.h = __float22bfloat162_rn(make_float2(a, b));   // v_cvt_pk_bf16_f32
    return x.u;
}

__device__ __forceinline__ float fexp2(float x) {
#if __has_builtin(__builtin_amdgcn_exp2f)
    return __builtin_amdgcn_exp2f(x);
#else
    return __expf(x * 0.69314718055994531f);
#endif
}

__device__ __forceinline__ f32x4 mfma16(bf16x4 a, bf16x4 b, f32x4 c) {
#if __has_builtin(__builtin_amdgcn_mfma_f32_16x16x16bf16_1k)
    return __builtin_amdgcn_mfma_f32_16x16x16bf16_1k(a, b, c, 0, 0, 0);
#else
    bf16x8 a8 = {a[0], a[1], a[2], a[3], 0, 0, 0, 0};
    bf16x8 b8 = {b[0], b[1], b[2], b[3], 0, 0, 0, 0};
    return __builtin_amdgcn_mfma_f32_16x16x32_bf16(a8, b8, c, 0, 0, 0);
#endif
}

__global__ __launch_bounds__(512, 4)
void fattn_kernel(const float* __restrict__ qg,
                  const float* __restrict__ kg,
                  const float* __restrict__ vg,
                  const float* __restrict__ maskg,
                  float* __restrict__ outg)
{
    __shared__ __attribute__((aligned(16))) ushort Ks[3][BK * LDK];  // row=key, col=d
    __shared__ __attribute__((aligned(16))) ushort Vt[3][D_ * LDK];  // row=d, swizzled granules
    __shared__ __attribute__((aligned(16))) float  Em[S_];           // mask * log2e

    const int qt = blockIdx.x, h = blockIdx.y, b = blockIdx.z;
    const int tid = threadIdx.x;
    const int w = tid >> 6, lane = tid & 63, g = lane >> 4, l15 = lane & 15;
    const int gh = g >> 1, glo = g & 1, h3 = l15 >> 3;

    // ---- stage pre-scaled mask to LDS (once) ----
    {
        float4 mv = *(const float4*)(maskg + (size_t)b * S_ + tid * 4);
        *(float4*)&Em[tid * 4] = make_float4(mv.x * LOG2E, mv.y * LOG2E,
                                             mv.z * LOG2E, mv.w * LOG2E);
    }

    // ---- Q fragment (B-operand, x32), scale folded in ----
    const int qrow = qt * BQ + w * 16 + l15;
    const float* qp = qg + (size_t)(b * S_ + qrow) * ROWSZ + h * D_;
    bf16x8 qf[2];
#pragma unroll
    for (int half = 0; half < 2; ++half) {
        float4 f0 = *(const float4*)(qp + half * 32 + g * 8);
        float4 f1 = *(const float4*)(qp + half * 32 + g * 8 + 4);
        union { bf16x8 v; uint4 u; } x;
        x.u = make_uint4(pack2(f0.x * SCALE2, f0.y * SCALE2),
                         pack2(f0.z * SCALE2, f0.w * SCALE2),
                         pack2(f1.x * SCALE2, f1.y * SCALE2),
                         pack2(f1.z * SCALE2, f1.w * SCALE2));
        qf[half] = x.v;
    }

    // staging maps (r7-identical)
    const int skey16 = tid >> 4;
    const int sd4    = (tid & 15) * 4;
    const int svd    = lane;
    const int svk8   = w * 8;
    const int vphys  = (w ^ ((lane >> 3) & 7)) * 8;

    const size_t kvbase = (size_t)b * S_ * ROWSZ + h * D_;

    float4 kpre0, kpre1;
    float  vpre[8];
    auto prefetch = [&](int kt) {
        const float* kb = kg + kvbase + (size_t)kt * BK * ROWSZ;
        kpre0 = *(const float4*)(kb + (size_t)skey16 * ROWSZ + sd4);
        kpre1 = *(const float4*)(kb + (size_t)(skey16 + 32) * ROWSZ + sd4);
        const float* vb = vg + kvbase + (size_t)kt * BK * ROWSZ + svd;
#pragma unroll
        for (int i = 0; i < 8; ++i) vpre[i] = vb[(size_t)(svk8 + i) * ROWSZ];
    };
    auto stage = [&](int buf) {
        *(uint2*)&Ks[buf][skey16 * LDK + sd4] =
            make_uint2(pack2(kpre0.x, kpre0.y), pack2(kpre0.z, kpre0.w));
        *(uint2*)&Ks[buf][(skey16 + 32) * LDK + sd4] =
            make_uint2(pack2(kpre1.x, kpre1.y), pack2(kpre1.z, kpre1.w));
        *(uint4*)&Vt[buf][svd * LDK + vphys] =
            make_uint4(pack2(vpre[0], vpre[1]), pack2(vpre[2], vpre[3]),
                       pack2(vpre[4], vpre[5]), pack2(vpre[6], vpre[7]));
    };

    float l_r = 0.0f;
    f32x4 o_acc[4];
#pragma unroll
    for (int t = 0; t < 4; ++t) o_acc[t] = (f32x4){0.f, 0.f, 0.f, 0.f};

    const int koff  = l15 * LDK + g * 8;
    const int vbase = l15 * LDK + glo * 4;

    // scores chunk c of tile kt from Ks[buf] -> sv[c][*]
    auto qkchunk = [&](int kt, int buf, int c, float (&sv)[4][4]) {
        f32x4 acc = *(const f32x4*)&Em[kt * BK + c * 16 + g * 4];
        const ushort* ks = Ks[buf];
        bf16x8 kf0 = *(const bf16x8*)&ks[c * 16 * LDK + koff];
        bf16x8 kf1 = *(const bf16x8*)&ks[c * 16 * LDK + koff + 32];
        acc = __builtin_amdgcn_mfma_f32_16x16x32_bf16(kf0, qf[0], acc, 0, 0, 0);
        acc = __builtin_amdgcn_mfma_f32_16x16x32_bf16(kf1, qf[1], acc, 0, 0, 0);
        sv[c][0] = acc[0]; sv[c][1] = acc[1]; sv[c][2] = acc[2]; sv[c][3] = acc[3];
    };

    float svA[4][4], svB[4][4];

    // ---- prologue: fill pipeline ----
    prefetch(0); stage(0);
    prefetch(1);
    __syncthreads();                        // buf0 ready (also covers Em)
#pragma unroll
    for (int c = 0; c < 4; ++c) qkchunk(0, 0, c, svA);
    stage(1);
    prefetch(2);
    __syncthreads();                        // buf1 ready

    // ---- braided main loop: softmax(kt) | QK(kt+1) | PV(kt) per c-chunk ----
    auto body = [&](int kt, float (&scur)[4][4], float (&snxt)[4][4]) {
        const int bcur = kt % 3, bnxt = (kt + 1) % 3, bstg = (kt + 2) % 3;
        const ushort* vt = Vt[bcur];
        const bool do_next = (kt + 1 < NT);
        float rs = 0.f;
#pragma unroll
        for (int c = 0; c < 4; ++c) {
            // softmax chunk (VALU stream)
            float p0 = fexp2(scur[c][0]), p1 = fexp2(scur[c][1]);
            float p2 = fexp2(scur[c][2]), p3 = fexp2(scur[c][3]);
            rs += (p0 + p1) + (p2 + p3);
            union { bf16x4 v; uint2 u; } x;
            x.u = make_uint2(pack2(p0, p1), pack2(p2, p3));
            const bf16x4 pfc = x.v;
            // next tile's QK chunk (independent LDS+MFMA stream)
            if (do_next) qkchunk(kt + 1, bnxt, c, snxt);
            // PV chunk (LDS+MFMA stream)
#pragma unroll
            for (int t2 = 0; t2 < 4; ++t2) {
                const int e = (2 * t2 + h3) & 7;
                const int physu = (2 * c + gh) ^ e;
                bf16x4 vf = *(const bf16x4*)&vt[t2 * 16 * LDK + vbase + physu * 8];
                o_acc[t2] = mfma16(vf, pfc, o_acc[t2]);
            }
        }
        l_r += rs;
        if (kt + 2 < NT) stage(bstg);
        if (kt + 3 < NT) prefetch(kt + 3);
        if (kt + 1 < NT) __syncthreads();
    };

    for (int k2 = 0; k2 < NT; k2 += 2) {    // NT even; ping-pong sv arrays
        body(k2,     svA, svB);
        body(k2 + 1, svB, svA);
    }

    // ---- epilogue: reduce l across quads, normalize, store fp32 ----
    l_r += __shfl_xor(l_r, 16);
    l_r += __shfl_xor(l_r, 32);
    const float inv = 1.0f / l_r;
    float* op = outg + (size_t)(b * S_ + qrow) * ROWSZ + h * D_;
#pragma unroll
    for (int t2 = 0; t2 < 4; ++t2)
#pragma unroll
        for (int r = 0; r < 4; ++r)
            op[t2 * 16 + g * 4 + r] = o_acc[t2][r] * inv;
}

extern "C" void kernel_launch(void* const* d_in, const int* in_sizes, int n_in,
                              void* d_out, int out_size, void* d_ws, size_t ws_size,
                              hipStream_t stream) {
    dim3 grid(S_ / BQ, H_, B_);   // (16,16,2) = 512 blocks, 2/CU
    fattn_kernel<<<grid, dim3(512), 0, stream>>>(
        (const float*)d_in[0], (const float*)d_in[1], (const float*)d_in[2],
        (const float*)d_in[3], (float*)d_out);
}